// Round 1
// baseline (460.649 us; speedup 1.0000x reference)
//
#include <hip/hip_runtime.h>
#include <hip/hip_bf16.h>
#include <math.h>

#define N_EMBD 768
#define N_HEAD 12
#define BATCH  2
#define SEQ    2048
#define ROWS   (BATCH*SEQ)   // 4096
#define C3     (3*N_EMBD)    // 2304

typedef __bf16 bf16;
typedef __attribute__((ext_vector_type(8))) __bf16 bf16x8;
typedef __attribute__((ext_vector_type(4))) float f32x4;

// ---------------- transpose + fp32->bf16 cast: in[K,N] -> out[N,K] ----------------
__global__ __launch_bounds__(256) void k_transpose_cast(
    const float* __restrict__ in, bf16* __restrict__ out, int K, int N)
{
    __shared__ bf16 tile[32][33];
    int n0 = blockIdx.x * 32, k0 = blockIdx.y * 32;
    int tc = threadIdx.x & 31, tr = threadIdx.x >> 5;  // tr 0..7
    #pragma unroll
    for (int i = 0; i < 4; i++) {
        int r = tr + i * 8;
        tile[r][tc] = (bf16)in[(size_t)(k0 + r) * N + n0 + tc];
    }
    __syncthreads();
    #pragma unroll
    for (int i = 0; i < 4; i++) {
        int r = tr + i * 8;
        out[(size_t)(n0 + r) * K + k0 + tc] = tile[tc][r];
    }
}

// ---------------- LayerNorm fp32 -> bf16, one wave per row (768 cols) ----------------
__global__ __launch_bounds__(256) void k_layernorm(
    const float* __restrict__ x, const float* __restrict__ g,
    const float* __restrict__ b, bf16* __restrict__ out)
{
    int wave = threadIdx.x >> 6, lane = threadIdx.x & 63;
    int row = blockIdx.x * 4 + wave;
    const float* xr = x + (size_t)row * N_EMBD;
    float v[12];
    float s = 0.f, sq = 0.f;
    #pragma unroll
    for (int i = 0; i < 12; i++) {
        v[i] = xr[lane + 64 * i];
        s += v[i]; sq += v[i] * v[i];
    }
    #pragma unroll
    for (int off = 32; off > 0; off >>= 1) {
        s  += __shfl_xor(s, off);
        sq += __shfl_xor(sq, off);
    }
    float mu  = s * (1.f / N_EMBD);
    float var = sq * (1.f / N_EMBD) - mu * mu;
    float rs  = rsqrtf(var + 1e-5f);
    bf16* orow = out + (size_t)row * N_EMBD;
    #pragma unroll
    for (int i = 0; i < 12; i++) {
        int c = lane + 64 * i;
        orow[c] = (bf16)((v[i] - mu) * rs * g[c] + b[c]);
    }
}

// ---------------- GEMM: out = act(A[M,K] @ Bt[N,K]^T + bias) (+res), m93-style ----------------
// ACT: 0=none, 1=gelu.  RES: add fp32 residual [M,N].  OUT_BF16: write bf16 else fp32.
template<int ACT, bool RES, bool OUT_BF16>
__global__ __launch_bounds__(256) void k_gemm(
    const bf16* __restrict__ A, const bf16* __restrict__ Bt,
    const float* __restrict__ bias, const float* __restrict__ res,
    void* __restrict__ outp, int M, int N, int K)
{
    __shared__ __align__(16) bf16 As[128 * 32];
    __shared__ __align__(16) bf16 Bs[128 * 32];
    int n0 = blockIdx.x * 128, m0 = blockIdx.y * 128;
    int t = threadIdx.x;
    int lane = t & 63, wave = t >> 6;
    int wr = wave >> 1, wc = wave & 1;
    int quad = lane >> 4, l16 = lane & 15;

    f32x4 acc[4][4];
    #pragma unroll
    for (int i = 0; i < 4; i++)
        #pragma unroll
        for (int j = 0; j < 4; j++) acc[i][j] = (f32x4){0.f, 0.f, 0.f, 0.f};

    int srow = t >> 2;          // 0..63
    int skk  = (t & 3) * 8;     // 0,8,16,24

    for (int k0 = 0; k0 < K; k0 += 32) {
        __syncthreads();
        #pragma unroll
        for (int p = 0; p < 2; p++) {
            int r = srow + p * 64;
            *(uint4*)&As[r * 32 + skk] = *(const uint4*)&A [(size_t)(m0 + r) * K + k0 + skk];
            *(uint4*)&Bs[r * 32 + skk] = *(const uint4*)&Bt[(size_t)(n0 + r) * K + k0 + skk];
        }
        __syncthreads();
        bf16x8 af[4], bfv[4];
        #pragma unroll
        for (int i = 0; i < 4; i++) af[i]  = *(bf16x8*)&As[(wr * 64 + i * 16 + l16) * 32 + quad * 8];
        #pragma unroll
        for (int j = 0; j < 4; j++) bfv[j] = *(bf16x8*)&Bs[(wc * 64 + j * 16 + l16) * 32 + quad * 8];
        #pragma unroll
        for (int i = 0; i < 4; i++)
            #pragma unroll
            for (int j = 0; j < 4; j++)
                acc[i][j] = __builtin_amdgcn_mfma_f32_16x16x32_bf16(af[i], bfv[j], acc[i][j], 0, 0, 0);
    }

    float* outf = (float*)outp;
    bf16*  outb = (bf16*)outp;
    #pragma unroll
    for (int i = 0; i < 4; i++) {
        #pragma unroll
        for (int j = 0; j < 4; j++) {
            int col = n0 + wc * 64 + j * 16 + l16;
            float bv = bias[col];
            #pragma unroll
            for (int r = 0; r < 4; r++) {
                int row = m0 + wr * 64 + i * 16 + quad * 4 + r;
                float v = acc[i][j][r] + bv;
                if (ACT == 1) {
                    float z = 0.7978845608f * (v + 0.044715f * v * v * v);
                    v = 0.5f * v * (1.f + tanhf(z));
                }
                if (RES) v += res[(size_t)row * N + col];
                if (OUT_BF16) outb[(size_t)row * N + col] = (bf16)v;
                else          outf[(size_t)row * N + col] = v;
            }
        }
    }
}

// ---------------- Flash attention (causal), bf16 MFMA, online softmax ----------------
// qkv: [ROWS, 2304] bf16 (q|k|v each 768). y: [ROWS, 768] bf16.
// Block: 4 waves; wave handles 16 q rows; block handles 64 q rows of one (b,h).
__global__ __launch_bounds__(256) void k_flash(
    const bf16* __restrict__ qkv, bf16* __restrict__ y)
{
    __shared__ __align__(16) bf16 Ks[32 * 64];     // [key][d]
    __shared__ __align__(16) bf16 VT[64 * 32];     // [d][key]
    __shared__ __align__(16) bf16 Ps[4][16 * 32];  // per-wave [q][key]
    int qt = blockIdx.x;           // 0..31
    int bh = blockIdx.y;           // 0..23
    int b = bh / N_HEAD, h = bh % N_HEAD;
    size_t base = (size_t)b * SEQ * C3;
    int t = threadIdx.x, lane = t & 63, wave = t >> 6;
    int quad = lane >> 4, l16 = lane & 15;
    int qbase = qt * 64 + wave * 16;

    // Q fragments, pre-scaled by 1/sqrt(64)=0.125 (exact in bf16)
    bf16x8 qa[2];
    {
        const bf16* qrow = qkv + base + (size_t)(qbase + l16) * C3 + h * 64;
        #pragma unroll
        for (int hh = 0; hh < 2; hh++) {
            union { uint4 u; bf16 e[8]; bf16x8 v; } uq;
            uq.u = *(const uint4*)&qrow[quad * 8 + hh * 32];
            #pragma unroll
            for (int j = 0; j < 8; j++) uq.e[j] = (bf16)((float)uq.e[j] * 0.125f);
            qa[hh] = uq.v;
        }
    }
    float m_old[4], l_sum[4];
    #pragma unroll
    for (int r = 0; r < 4; r++) { m_old[r] = -1e30f; l_sum[r] = 0.f; }
    f32x4 o[4];
    #pragma unroll
    for (int j = 0; j < 4; j++) o[j] = (f32x4){0.f, 0.f, 0.f, 0.f};

    int kmax = qt * 64 + 63;
    int skk = t >> 3;           // 0..31 (key within tile)
    int sd  = (t & 7) * 8;      // 0..56 (d chunk)

    for (int k0 = 0; k0 <= kmax; k0 += 32) {
        __syncthreads();
        {   // stage K (natural) and V (transposed)
            const bf16* krow = qkv + base + (size_t)(k0 + skk) * C3 + N_EMBD + h * 64 + sd;
            *(uint4*)&Ks[skk * 64 + sd] = *(const uint4*)krow;
            const bf16* vrow = qkv + base + (size_t)(k0 + skk) * C3 + 2 * N_EMBD + h * 64 + sd;
            union { uint4 u; bf16 e[8]; } uv;
            uv.u = *(const uint4*)vrow;
            #pragma unroll
            for (int j = 0; j < 8; j++) VT[(sd + j) * 32 + skk] = uv.e[j];
        }
        __syncthreads();

        // S = Q K^T  (two 16-key n-tiles)
        f32x4 s[2];
        #pragma unroll
        for (int nt = 0; nt < 2; nt++) {
            bf16x8 b0 = *(bf16x8*)&Ks[(nt * 16 + l16) * 64 + quad * 8];
            bf16x8 b1 = *(bf16x8*)&Ks[(nt * 16 + l16) * 64 + 32 + quad * 8];
            f32x4 z = (f32x4){0.f, 0.f, 0.f, 0.f};
            z = __builtin_amdgcn_mfma_f32_16x16x32_bf16(qa[0], b0, z, 0, 0, 0);
            z = __builtin_amdgcn_mfma_f32_16x16x32_bf16(qa[1], b1, z, 0, 0, 0);
            s[nt] = z;
        }
        // causal mask (finite sentinel avoids inf-inf NaN)
        #pragma unroll
        for (int nt = 0; nt < 2; nt++) {
            int key = k0 + nt * 16 + l16;
            #pragma unroll
            for (int r = 0; r < 4; r++) {
                int q = qbase + quad * 4 + r;
                if (key > q) s[nt][r] = -1e30f;
            }
        }
        // online softmax (row stats live in 16-lane groups, reg r = row%4)
        float p0[4], p1[4], alpha[4];
        #pragma unroll
        for (int r = 0; r < 4; r++) {
            float cur = fmaxf(s[0][r], s[1][r]);
            #pragma unroll
            for (int off = 8; off > 0; off >>= 1) cur = fmaxf(cur, __shfl_xor(cur, off));
            float m_new = fmaxf(m_old[r], cur);
            alpha[r] = __expf(m_old[r] - m_new);
            p0[r] = __expf(s[0][r] - m_new);
            p1[r] = __expf(s[1][r] - m_new);
            float ps = p0[r] + p1[r];
            #pragma unroll
            for (int off = 8; off > 0; off >>= 1) ps += __shfl_xor(ps, off);
            l_sum[r] = l_sum[r] * alpha[r] + ps;
            m_old[r] = m_new;
        }
        #pragma unroll
        for (int j = 0; j < 4; j++)
            #pragma unroll
            for (int r = 0; r < 4; r++) o[j][r] *= alpha[r];

        // P: C-layout -> LDS -> A-layout (per-wave region)
        #pragma unroll
        for (int r = 0; r < 4; r++) {
            Ps[wave][(quad * 4 + r) * 32 +      l16] = (bf16)p0[r];
            Ps[wave][(quad * 4 + r) * 32 + 16 + l16] = (bf16)p1[r];
        }
        __syncthreads();  // safety: cross-lane LDS visibility before A-frag read
        bf16x8 pa = *(bf16x8*)&Ps[wave][l16 * 32 + quad * 8];
        #pragma unroll
        for (int j = 0; j < 4; j++) {
            bf16x8 vb = *(bf16x8*)&VT[(j * 16 + l16) * 32 + quad * 8];
            o[j] = __builtin_amdgcn_mfma_f32_16x16x32_bf16(pa, vb, o[j], 0, 0, 0);
        }
    }
    // epilogue: divide by l, write y
    #pragma unroll
    for (int j = 0; j < 4; j++) {
        #pragma unroll
        for (int r = 0; r < 4; r++) {
            int q = qbase + quad * 4 + r;
            float val = o[j][r] / l_sum[r];
            y[(size_t)(b * SEQ + q) * N_EMBD + h * 64 + j * 16 + l16] = (bf16)val;
        }
    }
}

// ---------------- launcher ----------------
extern "C" void kernel_launch(void* const* d_in, const int* in_sizes, int n_in,
                              void* d_out, int out_size, void* d_ws, size_t ws_size,
                              hipStream_t stream) {
    const float* x           = (const float*)d_in[0];
    const float* ln1_g       = (const float*)d_in[1];
    const float* ln1_b       = (const float*)d_in[2];
    const float* w_attn      = (const float*)d_in[3];
    const float* b_attn      = (const float*)d_in[4];
    const float* w_attn_proj = (const float*)d_in[5];
    const float* b_attn_proj = (const float*)d_in[6];
    const float* ln2_g       = (const float*)d_in[7];
    const float* ln2_b       = (const float*)d_in[8];
    const float* w_fc        = (const float*)d_in[9];
    const float* b_fc        = (const float*)d_in[10];
    const float* w_mlp_proj  = (const float*)d_in[11];
    const float* b_mlp_proj  = (const float*)d_in[12];

    char* ws = (char*)d_ws;
    size_t off = 0;
    auto alloc = [&](size_t n) -> void* {
        off = (off + 255) & ~(size_t)255;
        void* p = ws + off;
        off += n;
        return p;
    };
    bf16* wqkvT  = (bf16*)alloc((size_t)C3 * N_EMBD * 2);
    bf16* wprojT = (bf16*)alloc((size_t)N_EMBD * N_EMBD * 2);
    bf16* wfcT   = (bf16*)alloc((size_t)4 * N_EMBD * N_EMBD * 2);
    bf16* wmlpT  = (bf16*)alloc((size_t)N_EMBD * 4 * N_EMBD * 2);
    bf16* hbuf   = (bf16*)alloc((size_t)ROWS * N_EMBD * 2);           // h1 then h2
    float* x2    = (float*)alloc((size_t)ROWS * N_EMBD * 4);
    bf16* yb     = (bf16*)alloc((size_t)ROWS * N_EMBD * 2);
    bf16* big    = (bf16*)alloc((size_t)ROWS * 4 * N_EMBD * 2);       // qkv then act
    bf16* qkvb   = big;        // [ROWS, 2304]
    bf16* actb   = big;        // [ROWS, 3072]

    // weights -> bf16 transposed [N,K]
    k_transpose_cast<<<dim3(C3 / 32,     N_EMBD / 32),   256, 0, stream>>>(w_attn,      wqkvT,  N_EMBD,   C3);
    k_transpose_cast<<<dim3(N_EMBD / 32, N_EMBD / 32),   256, 0, stream>>>(w_attn_proj, wprojT, N_EMBD,   N_EMBD);
    k_transpose_cast<<<dim3(3072 / 32,   N_EMBD / 32),   256, 0, stream>>>(w_fc,        wfcT,   N_EMBD,   3072);
    k_transpose_cast<<<dim3(N_EMBD / 32, 3072 / 32),     256, 0, stream>>>(w_mlp_proj,  wmlpT,  3072,     N_EMBD);

    k_layernorm<<<ROWS / 4, 256, 0, stream>>>(x, ln1_g, ln1_b, hbuf);
    k_gemm<0, false, true ><<<dim3(C3 / 128,   ROWS / 128), 256, 0, stream>>>(hbuf, wqkvT,  b_attn,      nullptr, qkvb, ROWS, C3,     N_EMBD);
    k_flash<<<dim3(SEQ / 64, BATCH * N_HEAD), 256, 0, stream>>>(qkvb, yb);
    k_gemm<0, true,  false><<<dim3(N_EMBD / 128, ROWS / 128), 256, 0, stream>>>(yb,   wprojT, b_attn_proj, x,       x2,   ROWS, N_EMBD, N_EMBD);
    k_layernorm<<<ROWS / 4, 256, 0, stream>>>(x2, ln2_g, ln2_b, hbuf);
    k_gemm<1, false, true ><<<dim3(3072 / 128,  ROWS / 128), 256, 0, stream>>>(hbuf, wfcT,   b_fc,        nullptr, actb, ROWS, 3072,   N_EMBD);
    k_gemm<0, true,  false><<<dim3(N_EMBD / 128, ROWS / 128), 256, 0, stream>>>(actb, wmlpT,  b_mlp_proj,  x2, (float*)d_out, ROWS, N_EMBD, 3072);
}

// Round 2
// 346.641 us; speedup vs baseline: 1.3289x; 1.3289x over previous
//
#include <hip/hip_runtime.h>
#include <hip/hip_bf16.h>
#include <math.h>

#define N_EMBD 768
#define N_HEAD 12
#define BATCH  2
#define SEQ    2048
#define ROWS   (BATCH*SEQ)   // 4096
#define C3     (3*N_EMBD)    // 2304

typedef __bf16 bf16;
typedef __attribute__((ext_vector_type(8))) __bf16 bf16x8;
typedef __attribute__((ext_vector_type(4))) float f32x4;

// async global->LDS, 16B per lane. LDS dest must be wave-uniform base + 16*lane.
__device__ __forceinline__ void async16(const bf16* g, bf16* l) {
    __builtin_amdgcn_global_load_lds(
        (const __attribute__((address_space(1))) uint32_t*)g,
        (__attribute__((address_space(3))) uint32_t*)l, 16, 0, 0);
}

// ---------------- transpose + fp32->bf16 cast: in[K,N] -> out[N,K] ----------------
__global__ __launch_bounds__(256) void k_transpose_cast(
    const float* __restrict__ in, bf16* __restrict__ out, int K, int N)
{
    __shared__ bf16 tile[32][33];
    int n0 = blockIdx.x * 32, k0 = blockIdx.y * 32;
    int tc = threadIdx.x & 31, tr = threadIdx.x >> 5;  // tr 0..7
    #pragma unroll
    for (int i = 0; i < 4; i++) {
        int r = tr + i * 8;
        tile[r][tc] = (bf16)in[(size_t)(k0 + r) * N + n0 + tc];
    }
    __syncthreads();
    #pragma unroll
    for (int i = 0; i < 4; i++) {
        int r = tr + i * 8;
        out[(size_t)(n0 + r) * K + k0 + tc] = tile[tc][r];
    }
}

// ---------------- LayerNorm fp32 -> bf16, one wave per row (768 cols) ----------------
__global__ __launch_bounds__(256) void k_layernorm(
    const float* __restrict__ x, const float* __restrict__ g,
    const float* __restrict__ b, bf16* __restrict__ out)
{
    int wave = threadIdx.x >> 6, lane = threadIdx.x & 63;
    int row = blockIdx.x * 4 + wave;
    const float* xr = x + (size_t)row * N_EMBD;
    float v[12];
    float s = 0.f, sq = 0.f;
    #pragma unroll
    for (int i = 0; i < 12; i++) {
        v[i] = xr[lane + 64 * i];
        s += v[i]; sq += v[i] * v[i];
    }
    #pragma unroll
    for (int off = 32; off > 0; off >>= 1) {
        s  += __shfl_xor(s, off);
        sq += __shfl_xor(sq, off);
    }
    float mu  = s * (1.f / N_EMBD);
    float var = sq * (1.f / N_EMBD) - mu * mu;
    float rs  = rsqrtf(var + 1e-5f);
    bf16* orow = out + (size_t)row * N_EMBD;
    #pragma unroll
    for (int i = 0; i < 12; i++) {
        int c = lane + 64 * i;
        orow[c] = (bf16)((v[i] - mu) * rs * g[c] + b[c]);
    }
}

// ---------------- GEMM: out = act(A[M,K] @ Bt[N,K]^T + bias) (+res) ----------------
// 128xBN tile, global_load_lds staging (m97 structure).
// ACT: 0=none, 1=gelu. RES: add fp32 residual. OUT_BF16: bf16 else fp32 output.
template<int BN, int ACT, bool RES, bool OUT_BF16>
__global__ __launch_bounds__(256) void k_gemm(
    const bf16* __restrict__ A, const bf16* __restrict__ Bt,
    const float* __restrict__ bias, const float* __restrict__ res,
    void* __restrict__ outp, int M, int N, int K)
{
    constexpr int WC  = BN / 64;        // waves along N (2 for BN=128, 1 for BN=64)
    constexpr int WR  = 4 / WC;         // waves along M
    constexpr int RPW = 128 / WR;       // rows per wave (64 or 32)
    constexpr int MI  = RPW / 16;       // m-tiles per wave (4 or 2)
    __shared__ __align__(16) bf16 As[128 * 32];
    __shared__ __align__(16) bf16 Bs[BN * 32];
    int n0 = blockIdx.x * BN, m0 = blockIdx.y * 128;
    int t = threadIdx.x;
    int lane = t & 63, wave = t >> 6;
    int wr = wave / WC, wc = wave % WC;
    int quad = lane >> 4, l16 = lane & 15;

    f32x4 acc[MI][4];
    #pragma unroll
    for (int i = 0; i < MI; i++)
        #pragma unroll
        for (int j = 0; j < 4; j++) acc[i][j] = (f32x4){0.f, 0.f, 0.f, 0.f};

    int srow = t >> 2;          // 0..63
    int skk  = (t & 3) * 8;     // 0,8,16,24

    for (int k0 = 0; k0 < K; k0 += 32) {
        __syncthreads();
        #pragma unroll
        for (int p = 0; p < 2; p++) {
            int r = srow + p * 64;
            async16(&A[(size_t)(m0 + r) * K + k0 + skk], &As[r * 32 + skk]);
        }
        #pragma unroll
        for (int p = 0; p < BN / 64; p++) {
            int r = srow + p * 64;
            async16(&Bt[(size_t)(n0 + r) * K + k0 + skk], &Bs[r * 32 + skk]);
        }
        __syncthreads();
        bf16x8 af[MI], bfv[4];
        #pragma unroll
        for (int i = 0; i < MI; i++) af[i]  = *(bf16x8*)&As[(wr * RPW + i * 16 + l16) * 32 + quad * 8];
        #pragma unroll
        for (int j = 0; j < 4; j++)  bfv[j] = *(bf16x8*)&Bs[(wc * 64 + j * 16 + l16) * 32 + quad * 8];
        #pragma unroll
        for (int i = 0; i < MI; i++)
            #pragma unroll
            for (int j = 0; j < 4; j++)
                acc[i][j] = __builtin_amdgcn_mfma_f32_16x16x32_bf16(af[i], bfv[j], acc[i][j], 0, 0, 0);
    }

    float* outf = (float*)outp;
    bf16*  outb = (bf16*)outp;
    #pragma unroll
    for (int i = 0; i < MI; i++) {
        #pragma unroll
        for (int j = 0; j < 4; j++) {
            int col = n0 + wc * 64 + j * 16 + l16;
            float bv = bias[col];
            #pragma unroll
            for (int r = 0; r < 4; r++) {
                int row = m0 + wr * RPW + i * 16 + quad * 4 + r;
                float v = acc[i][j][r] + bv;
                if (ACT == 1) {
                    float z = 0.7978845608f * (v + 0.044715f * v * v * v);
                    v = v / (1.f + __expf(-2.f * z));   // 0.5v(1+tanh z) == v*sigmoid(2z)
                }
                if (RES) v += res[(size_t)row * N + col];
                if (OUT_BF16) outb[(size_t)row * N + col] = (bf16)v;
                else          outf[(size_t)row * N + col] = v;
            }
        }
    }
}

// ---------------- Flash attention (causal), 64-key tiles, swizzled VT ----------------
// qkv: [ROWS, 2304] bf16 (q|k|v each 768). y: [ROWS, 768] bf16.
// 1D grid of 768 blocks: bh = bid%24, qt = bid/24 (spreads work across CUs).
#define PS_S 72   // Ps stride: 16B-aligned reads, conflict-free writes
__global__ __launch_bounds__(256) void k_flash(
    const bf16* __restrict__ qkv, bf16* __restrict__ y)
{
    __shared__ __align__(16) bf16 Ks[64 * 64];        // [key][d], natural
    __shared__ __align__(16) bf16 VT[64 * 64];        // [d][key^swz]
    __shared__ __align__(16) bf16 Ps[4][16 * PS_S];   // per-wave [q][key]
    int bid = blockIdx.x;
    int bh = bid % 24, qt = bid / 24;
    int b = bh / N_HEAD, h = bh % N_HEAD;
    size_t base = (size_t)b * SEQ * C3;
    int t = threadIdx.x, lane = t & 63, wave = t >> 6;
    int quad = lane >> 4, l16 = lane & 15;
    int qbase = qt * 64 + wave * 16;

    // Q fragments, pre-scaled by 1/sqrt(64)=0.125 (exact in bf16)
    bf16x8 qa[2];
    {
        const bf16* qrow = qkv + base + (size_t)(qbase + l16) * C3 + h * 64;
        #pragma unroll
        for (int hh = 0; hh < 2; hh++) {
            union { uint4 u; bf16 e[8]; bf16x8 v; } uq;
            uq.u = *(const uint4*)&qrow[quad * 8 + hh * 32];
            #pragma unroll
            for (int j = 0; j < 8; j++) uq.e[j] = (bf16)((float)uq.e[j] * 0.125f);
            qa[hh] = uq.v;
        }
    }
    float m_old[4], l_sum[4];
    #pragma unroll
    for (int r = 0; r < 4; r++) { m_old[r] = -1e30f; l_sum[r] = 0.f; }
    f32x4 o[4];
    #pragma unroll
    for (int j = 0; j < 4; j++) o[j] = (f32x4){0.f, 0.f, 0.f, 0.f};

    int kk = t >> 3;            // 0..31 (key)
    int dd = (t & 7) * 8;       // 0..56 (d chunk)
    int vsw = (lane & 7) << 3;  // VT write swizzle for this lane

    for (int k0 = 0; k0 <= qt * 64; k0 += 64) {
        __syncthreads();
        #pragma unroll
        for (int p = 0; p < 2; p++) {
            int key = kk + 32 * p;
            const bf16* krow = qkv + base + (size_t)(k0 + key) * C3 + N_EMBD + h * 64 + dd;
            async16(krow, &Ks[key * 64 + dd]);                   // LDS off = 16t + 4096p
            const bf16* vrow = qkv + base + (size_t)(k0 + key) * C3 + 2 * N_EMBD + h * 64 + dd;
            union { uint4 u; bf16 e[8]; } uv;
            uv.u = *(const uint4*)vrow;
            int kw = key ^ vsw;                                   // swizzled column
            #pragma unroll
            for (int j = 0; j < 8; j++) VT[(dd + j) * 64 + kw] = uv.e[j];
        }
        __syncthreads();

        // S = Q K^T : 4 key-tiles of 16
        f32x4 s[4];
        #pragma unroll
        for (int nt = 0; nt < 4; nt++) {
            bf16x8 b0 = *(bf16x8*)&Ks[(nt * 16 + l16) * 64 + quad * 8];
            bf16x8 b1 = *(bf16x8*)&Ks[(nt * 16 + l16) * 64 + 32 + quad * 8];
            f32x4 z = (f32x4){0.f, 0.f, 0.f, 0.f};
            z = __builtin_amdgcn_mfma_f32_16x16x32_bf16(qa[0], b0, z, 0, 0, 0);
            z = __builtin_amdgcn_mfma_f32_16x16x32_bf16(qa[1], b1, z, 0, 0, 0);
            s[nt] = z;
        }
        // causal mask
        #pragma unroll
        for (int nt = 0; nt < 4; nt++) {
            int key = k0 + nt * 16 + l16;
            #pragma unroll
            for (int r = 0; r < 4; r++) {
                int q = qbase + quad * 4 + r;
                if (key > q) s[nt][r] = -1e30f;
            }
        }
        // online softmax (rows live across the 16-lane group)
        float p[4][4], alpha[4];
        #pragma unroll
        for (int r = 0; r < 4; r++) {
            float cur = fmaxf(fmaxf(s[0][r], s[1][r]), fmaxf(s[2][r], s[3][r]));
            #pragma unroll
            for (int off = 8; off > 0; off >>= 1) cur = fmaxf(cur, __shfl_xor(cur, off));
            float m_new = fmaxf(m_old[r], cur);
            alpha[r] = __expf(m_old[r] - m_new);
            float ps = 0.f;
            #pragma unroll
            for (int nt = 0; nt < 4; nt++) { p[nt][r] = __expf(s[nt][r] - m_new); ps += p[nt][r]; }
            #pragma unroll
            for (int off = 8; off > 0; off >>= 1) ps += __shfl_xor(ps, off);
            l_sum[r] = l_sum[r] * alpha[r] + ps;
            m_old[r] = m_new;
        }
        #pragma unroll
        for (int j = 0; j < 4; j++)
            #pragma unroll
            for (int r = 0; r < 4; r++) o[j][r] *= alpha[r];

        // P: C-layout -> per-wave LDS -> A-layout (no block barrier needed)
        #pragma unroll
        for (int nt = 0; nt < 4; nt++)
            #pragma unroll
            for (int r = 0; r < 4; r++)
                Ps[wave][(quad * 4 + r) * PS_S + nt * 16 + l16] = (bf16)p[nt][r];
        bf16x8 pa[2];
        #pragma unroll
        for (int kt = 0; kt < 2; kt++)
            pa[kt] = *(bf16x8*)&Ps[wave][l16 * PS_S + kt * 32 + quad * 8];
        // O += P V : VT is swizzled [d][key]
        #pragma unroll
        for (int jt = 0; jt < 4; jt++) {
            int d = jt * 16 + l16;
            int sw = ((d >> 3) & 7) << 3;
            #pragma unroll
            for (int kt = 0; kt < 2; kt++) {
                int kb = quad * 8 + kt * 32;
                bf16x8 vb = *(bf16x8*)&VT[d * 64 + (kb ^ sw)];
                o[jt] = __builtin_amdgcn_mfma_f32_16x16x32_bf16(pa[kt], vb, o[jt], 0, 0, 0);
            }
        }
    }
    // epilogue
    #pragma unroll
    for (int jt = 0; jt < 4; jt++) {
        #pragma unroll
        for (int r = 0; r < 4; r++) {
            int q = qbase + quad * 4 + r;
            float val = o[jt][r] / l_sum[r];
            y[(size_t)(b * SEQ + q) * N_EMBD + h * 64 + jt * 16 + l16] = (bf16)val;
        }
    }
}

// ---------------- launcher ----------------
extern "C" void kernel_launch(void* const* d_in, const int* in_sizes, int n_in,
                              void* d_out, int out_size, void* d_ws, size_t ws_size,
                              hipStream_t stream) {
    const float* x           = (const float*)d_in[0];
    const float* ln1_g       = (const float*)d_in[1];
    const float* ln1_b       = (const float*)d_in[2];
    const float* w_attn      = (const float*)d_in[3];
    const float* b_attn      = (const float*)d_in[4];
    const float* w_attn_proj = (const float*)d_in[5];
    const float* b_attn_proj = (const float*)d_in[6];
    const float* ln2_g       = (const float*)d_in[7];
    const float* ln2_b       = (const float*)d_in[8];
    const float* w_fc        = (const float*)d_in[9];
    const float* b_fc        = (const float*)d_in[10];
    const float* w_mlp_proj  = (const float*)d_in[11];
    const float* b_mlp_proj  = (const float*)d_in[12];

    char* ws = (char*)d_ws;
    size_t off = 0;
    auto alloc = [&](size_t n) -> void* {
        off = (off + 255) & ~(size_t)255;
        void* p = ws + off;
        off += n;
        return p;
    };
    bf16* wqkvT  = (bf16*)alloc((size_t)C3 * N_EMBD * 2);
    bf16* wprojT = (bf16*)alloc((size_t)N_EMBD * N_EMBD * 2);
    bf16* wfcT   = (bf16*)alloc((size_t)4 * N_EMBD * N_EMBD * 2);
    bf16* wmlpT  = (bf16*)alloc((size_t)N_EMBD * 4 * N_EMBD * 2);
    bf16* hbuf   = (bf16*)alloc((size_t)ROWS * N_EMBD * 2);
    float* x2    = (float*)alloc((size_t)ROWS * N_EMBD * 4);
    bf16* yb     = (bf16*)alloc((size_t)ROWS * N_EMBD * 2);
    bf16* big    = (bf16*)alloc((size_t)ROWS * 4 * N_EMBD * 2);
    bf16* qkvb   = big;        // [ROWS, 2304]
    bf16* actb   = big;        // [ROWS, 3072]

    // weights -> bf16 transposed [N,K]
    k_transpose_cast<<<dim3(C3 / 32,     N_EMBD / 32), 256, 0, stream>>>(w_attn,      wqkvT,  N_EMBD, C3);
    k_transpose_cast<<<dim3(N_EMBD / 32, N_EMBD / 32), 256, 0, stream>>>(w_attn_proj, wprojT, N_EMBD, N_EMBD);
    k_transpose_cast<<<dim3(3072 / 32,   N_EMBD / 32), 256, 0, stream>>>(w_fc,        wfcT,   N_EMBD, 3072);
    k_transpose_cast<<<dim3(N_EMBD / 32, 3072 / 32),   256, 0, stream>>>(w_mlp_proj,  wmlpT,  3072,   N_EMBD);

    k_layernorm<<<ROWS / 4, 256, 0, stream>>>(x, ln1_g, ln1_b, hbuf);
    k_gemm<128, 0, false, true ><<<dim3(C3 / 128,  ROWS / 128), 256, 0, stream>>>(hbuf, wqkvT,  b_attn,      nullptr, qkvb, ROWS, C3,     N_EMBD);
    k_flash<<<SEQ / 64 * BATCH * N_HEAD, 256, 0, stream>>>(qkvb, yb);
    k_gemm<64,  0, true,  false><<<dim3(N_EMBD / 64, ROWS / 128), 256, 0, stream>>>(yb,   wprojT, b_attn_proj, x,       x2,   ROWS, N_EMBD, N_EMBD);
    k_layernorm<<<ROWS / 4, 256, 0, stream>>>(x2, ln2_g, ln2_b, hbuf);
    k_gemm<128, 1, false, true ><<<dim3(3072 / 128, ROWS / 128), 256, 0, stream>>>(hbuf, wfcT,   b_fc,        nullptr, actb, ROWS, 3072,   N_EMBD);
    k_gemm<64,  0, true,  false><<<dim3(N_EMBD / 64, ROWS / 128), 256, 0, stream>>>(actb, wmlpT,  b_mlp_proj,  x2, (float*)d_out, ROWS, N_EMBD, 3072);
}